// Round 1
// baseline (365.181 us; speedup 1.0000x reference)
//
#include <hip/hip_runtime.h>
#include <cstdint>

// Problem constants (fixed by reference)
#define NB      8
#define NN      4096
#define NCLS    80
#define MAXDET  300
#define NTH     1024

// Output float layout (flat, 16808 elements):
//   [0,     2400)  dummy_indices = -1.0
//   [2400,  4800)  scores
//   [4800, 14400)  boxes (B,300,4)
//   [14400,16800)  classes (as float)
//   [16800,16808)  n_det (as float)
#define OFF_IDX  0
#define OFF_SCR  2400
#define OFF_BOX  4800
#define OFF_CLS  14400
#define OFF_NDT  16800

// IoU > thr test, matching reference arithmetic exactly (no FMA contraction):
// lt=max, rb=min, wh=clip(rb-lt,0), inter=wh0*wh1, iou=inter/(area_cur+area_kept-inter)
__device__ __forceinline__ bool iou_gt(float c0, float c1, float c2, float c3,
                                       float t0, float t1, float t2, float t3,
                                       float tarea)
{
#pragma clang fp contract(off)
    float xx1 = fmaxf(c0, t0);
    float yy1 = fmaxf(c1, t1);
    float xx2 = fminf(c2, t2);
    float yy2 = fminf(c3, t3);
    float w = xx2 - xx1; w = fmaxf(w, 0.0f);
    float h = yy2 - yy1; h = fmaxf(h, 0.0f);
    float inter = w * h;
    float areac = (c2 - c0) * (c3 - c1);   // area of current (later) box
    float uni = areac + tarea - inter;     // area_i + area_j - inter (ref order)
    return (inter / uni) > 0.65f;
}

__global__ __launch_bounds__(NTH)
void nms_kernel(const float* __restrict__ scores,
                const float* __restrict__ boxes,
                const int*   __restrict__ classes,
                float*       __restrict__ out)
{
    const int b    = blockIdx.x;
    const int tid  = threadIdx.x;
    const int lane = tid & 63;
    const int wv   = tid >> 6;   // wave id 0..15

    __shared__ uint64_t       keys[NN];          // 32 KB (sort keys)
    __shared__ uint64_t       kwords[64];        // keep bitmask words
    __shared__ unsigned short order_[NN];        // 8 KB  sorted pos -> orig idx
    __shared__ unsigned short grouped[NN];       // 8 KB  class-major list of sorted positions
    __shared__ unsigned short ccnt2[NCLS][8];    // per (class, segment) counts -> offsets
    __shared__ unsigned char  clsb[NN];          // class of sorted pos
    __shared__ unsigned char  keepf[NN];         // keep flag of sorted pos
    __shared__ int            cbase[NCLS + 1];
    __shared__ int            ccnt[NCLS];
    __shared__ int            woff[64];
    __shared__ int            nvalid_sh, total_sh;

    const float4* boxes4 = reinterpret_cast<const float4*>(boxes);
    const int bN = b * NN;

    // ---- phase 0: fill static outputs (harness poisons d_out before timed runs)
    for (int s = tid; s < MAXDET; s += NTH) {
        out[OFF_IDX + b * MAXDET + s] = -1.0f;
        out[OFF_SCR + b * MAXDET + s] = 0.0f;
        int ob = OFF_BOX + (b * MAXDET + s) * 4;
        out[ob + 0] = 0.0f; out[ob + 1] = 0.0f;
        out[ob + 2] = 0.0f; out[ob + 3] = 0.0f;
        out[OFF_CLS + b * MAXDET + s] = 0.0f;
    }
    if (tid == 0) nvalid_sh = 0;
    __syncthreads();

    // ---- phase 1: build sort keys (score desc, then index desc == composite desc)
    int myv = 0;
    for (int i = tid; i < NN; i += NTH) {
        float s = scores[bN + i];
        unsigned u = __float_as_uint(s);
        unsigned m = (u & 0x80000000u) ? ~u : (u | 0x80000000u); // order-preserving map
        keys[i] = ((uint64_t)m << 32) | (unsigned)i;
        myv += (s > 0.05f) ? 1 : 0;
    }
    atomicAdd(&nvalid_sh, myv);

    // ---- phase 2: bitonic sort, descending (78 stages)
    for (int k = 2; k <= NN; k <<= 1) {
        for (int j = k >> 1; j >= 1; j >>= 1) {
            __syncthreads();
            for (int idx = tid; idx < NN / 2; idx += NTH) {
                int i  = ((idx & ~(j - 1)) << 1) | (idx & (j - 1));
                int ij = i | j;
                bool desc = ((i & k) == 0);
                uint64_t a = keys[i], c = keys[ij];
                bool sw = desc ? (a < c) : (a > c);
                if (sw) { keys[i] = c; keys[ij] = a; }
            }
        }
    }
    __syncthreads();

    // ---- phase 3: extract order, classes; init keep flags
    for (int p = tid; p < NN; p += NTH) {
        int orig = (int)(keys[p] & 0xFFFFu);
        order_[p] = (unsigned short)orig;
        clsb[p]   = (unsigned char)classes[bN + orig];
        keepf[p]  = 0;
    }
    __syncthreads();

    const int nvalid = nvalid_sh;  // valid boxes form a prefix of sorted order

    // ---- phase 4: stable class-major grouping of valid sorted positions
    if (tid < NCLS * 8) {
        int c = tid >> 3, seg = tid & 7;
        int p0 = seg * (NN / 8);
        int p1 = min(p0 + NN / 8, nvalid);
        int cnt = 0;
        for (int p = p0; p < p1; ++p) cnt += (clsb[p] == c) ? 1 : 0;
        ccnt2[c][seg] = (unsigned short)cnt;
    }
    __syncthreads();
    if (tid < NCLS) {
        int run = 0;
        for (int seg = 0; seg < 8; ++seg) {
            int v = ccnt2[tid][seg];
            ccnt2[tid][seg] = (unsigned short)run;
            run += v;
        }
        ccnt[tid] = run;
    }
    __syncthreads();
    if (tid == 0) {
        int run = 0;
        for (int c = 0; c < NCLS; ++c) { cbase[c] = run; run += ccnt[c]; }
        cbase[NCLS] = run;
    }
    __syncthreads();
    if (tid < NCLS * 8) {
        int c = tid >> 3, seg = tid & 7;
        int kk = cbase[c] + (int)ccnt2[c][seg];
        int p0 = seg * (NN / 8);
        int p1 = min(p0 + NN / 8, nvalid);
        for (int p = p0; p < p1; ++p)
            if (clsb[p] == c) grouped[kk++] = (unsigned short)p;
    }
    __syncthreads();

    // ---- phase 5: per-class greedy NMS; wave wv handles classes wv, wv+16, ...
    for (int c = wv; c < NCLS; c += 16) {
        int base = cbase[c];
        int nc   = cbase[c + 1] - base;
        if (nc <= 0) continue;

        // member boxes for m < min(nc,256) in registers: m = chunk*64 + lane
        float4 bx0 = make_float4(0, 0, 0, 0), bx1 = bx0, bx2 = bx0, bx3 = bx0;
        int nreg = nc < 256 ? nc : 256;
        {
            int m = lane;
            if (m < nreg) bx0 = boxes4[bN + order_[grouped[base + m]]];
            m = 64 + lane;
            if (m < nreg) bx1 = boxes4[bN + order_[grouped[base + m]]];
            m = 128 + lane;
            if (m < nreg) bx2 = boxes4[bN + order_[grouped[base + m]]];
            m = 192 + lane;
            if (m < nreg) bx3 = boxes4[bN + order_[grouped[base + m]]];
        }

        uint64_t supp = 0;  // bit j: member (j*64 + lane) suppressed
        for (int t = 0; t < nc; ++t) {
            int jt = t >> 6, lt = t & 63;
            uint64_t sbit = (supp >> jt) & 1ull;
            uint64_t am = __ballot(sbit == 0);
            if (!((am >> lt) & 1ull)) continue;   // t already suppressed

            int pt = grouped[base + t];
            if (lane == 0) keepf[pt] = 1;          // t is kept

            // fetch box t (uniform)
            float t0, t1, t2, t3;
            if (jt < 4) {
                float4 src = (jt == 0) ? bx0 : (jt == 1) ? bx1 : (jt == 2) ? bx2 : bx3;
                t0 = __shfl(src.x, lt);
                t1 = __shfl(src.y, lt);
                t2 = __shfl(src.z, lt);
                t3 = __shfl(src.w, lt);
            } else {
                float4 g = boxes4[bN + order_[pt]];
                t0 = g.x; t1 = g.y; t2 = g.z; t3 = g.w;
            }
            float tarea;
            {
#pragma clang fp contract(off)
                tarea = (t2 - t0) * (t3 - t1);
            }

            // suppress later members overlapping t
            int jmax = (nc + 63) >> 6;
            for (int j = jt; j < jmax; ++j) {
                int m = (j << 6) + lane;
                if (m <= t || m >= nc) continue;
                if ((supp >> j) & 1ull) continue;
                float c0, c1, c2, c3;
                if (j < 4) {
                    float4 src = (j == 0) ? bx0 : (j == 1) ? bx1 : (j == 2) ? bx2 : bx3;
                    c0 = src.x; c1 = src.y; c2 = src.z; c3 = src.w;
                } else {
                    float4 g = boxes4[bN + order_[grouped[base + m]]];
                    c0 = g.x; c1 = g.y; c2 = g.z; c3 = g.w;
                }
                if (iou_gt(c0, c1, c2, c3, t0, t1, t2, t3, tarea))
                    supp |= (1ull << j);
            }
        }
    }
    __syncthreads();

    // ---- phase 6: rank kept boxes (prefix popcount) and scatter top-300
    if (tid < 64) {
        uint64_t wd = 0;
        int p0 = tid << 6;
        for (int q = 0; q < 64; ++q)
            wd |= ((uint64_t)(keepf[p0 + q] & 1)) << q;
        kwords[tid] = wd;
    }
    __syncthreads();
    if (tid == 0) {
        int run = 0;
        for (int w = 0; w < 64; ++w) { woff[w] = run; run += __popcll(kwords[w]); }
        total_sh = run;
    }
    __syncthreads();
    int ndet = total_sh < MAXDET ? total_sh : MAXDET;
    for (int p = tid; p < NN; p += NTH) {
        if (!keepf[p]) continue;
        int w = p >> 6, q = p & 63;
        int rank = woff[w] + __popcll(kwords[w] & ((1ull << q) - 1ull));
        if (rank >= MAXDET) continue;
        int orig = order_[p];
        out[OFF_SCR + b * MAXDET + rank] = scores[bN + orig];
        float4 g = boxes4[bN + orig];
        int ob = OFF_BOX + (b * MAXDET + rank) * 4;
        out[ob + 0] = g.x; out[ob + 1] = g.y;
        out[ob + 2] = g.z; out[ob + 3] = g.w;
        out[OFF_CLS + b * MAXDET + rank] = (float)clsb[p];
    }
    if (tid == 0) out[OFF_NDT + b] = (float)ndet;
}

extern "C" void kernel_launch(void* const* d_in, const int* in_sizes, int n_in,
                              void* d_out, int out_size, void* d_ws, size_t ws_size,
                              hipStream_t stream)
{
    const float* scores  = (const float*)d_in[0];
    const float* boxes   = (const float*)d_in[1];
    const int*   classes = (const int*)d_in[2];
    float*       out     = (float*)d_out;
    hipLaunchKernelGGL(nms_kernel, dim3(NB), dim3(NTH), 0, stream,
                       scores, boxes, classes, out);
}

// Round 2
// 323.113 us; speedup vs baseline: 1.1302x; 1.1302x over previous
//
#include <hip/hip_runtime.h>
#include <cstdint>

// Problem constants (fixed by reference)
#define NB      8
#define NN      4096
#define NCLS    80
#define MAXDET  300
#define NTH     1024

// Output float layout (flat, 16808 elements)
#define OFF_IDX  0
#define OFF_SCR  2400
#define OFF_BOX  4800
#define OFF_CLS  14400
#define OFF_NDT  16800

// IoU > thr test, matching reference arithmetic exactly (no FMA contraction)
__device__ __forceinline__ bool iou_gt(float c0, float c1, float c2, float c3,
                                       float t0, float t1, float t2, float t3,
                                       float tarea)
{
#pragma clang fp contract(off)
    float xx1 = fmaxf(c0, t0);
    float yy1 = fmaxf(c1, t1);
    float xx2 = fminf(c2, t2);
    float yy2 = fminf(c3, t3);
    float w = xx2 - xx1; w = fmaxf(w, 0.0f);
    float h = yy2 - yy1; h = fmaxf(h, 0.0f);
    float inter = w * h;
    float areac = (c2 - c0) * (c3 - c1);
    float uni = areac + tarea - inter;
    return (inter / uni) > 0.65f;
}

__device__ __forceinline__ void ce64(uint64_t& a, uint64_t& b, bool desc)
{
    // a is at the lower index; desc => a keeps max
    uint64_t lo = (a < b) ? a : b;
    uint64_t hi = (a < b) ? b : a;
    a = desc ? hi : lo;
    b = desc ? lo : hi;
}

__global__ __launch_bounds__(NTH)
void nms_kernel(const float* __restrict__ scores,
                const float* __restrict__ boxes,
                const int*   __restrict__ classes,
                float*       __restrict__ out)
{
    const int b    = blockIdx.x;
    const int tid  = threadIdx.x;
    const int lane = tid & 63;
    const int wv   = tid >> 6;   // wave id 0..15

    // ---- LDS layout (~54 KB) ----
    __shared__ __align__(16) uint32_t khi[NN];   // 16 KB  sort keys hi; later ccount overlay
    __shared__ __align__(16) uint32_t klo[NN];   // 16 KB  sort keys lo
    __shared__ unsigned short order_[NN];        // 8 KB   sorted pos -> orig idx
    __shared__ unsigned short grouped[NN];       // 8 KB   class-major list of sorted positions
    __shared__ unsigned char  clsb[NN];          // 4 KB   class of sorted pos
    __shared__ uint64_t       kwords[64];        // keep bitmask over sorted positions
    __shared__ int            cbase[NCLS + 1];
    __shared__ int            ctot[NCLS];
    __shared__ int            woff[64];
    __shared__ int            nvalid_sh, total_sh;

    const float4* boxes4 = reinterpret_cast<const float4*>(boxes);
    const int bN = b * NN;

    // ---- phase 0: fill static outputs (harness poisons d_out before timed runs)
    for (int s = tid; s < MAXDET; s += NTH) {
        out[OFF_IDX + b * MAXDET + s] = -1.0f;
        out[OFF_SCR + b * MAXDET + s] = 0.0f;
        int ob = OFF_BOX + (b * MAXDET + s) * 4;
        out[ob + 0] = 0.0f; out[ob + 1] = 0.0f;
        out[ob + 2] = 0.0f; out[ob + 3] = 0.0f;
        out[OFF_CLS + b * MAXDET + s] = 0.0f;
    }
    if (tid == 0) nvalid_sh = 0;
    if (tid < 64) kwords[tid] = 0;
    __syncthreads();

    // ---- phase 1: build sort keys in REGISTERS (4 elements/thread, i = tid*4+e)
    const int base = tid << 2;
    uint64_t v[4];
    int myv = 0;
    {
        const float4* s4 = reinterpret_cast<const float4*>(scores + bN);
        float4 sv = s4[tid];
        float ss[4] = {sv.x, sv.y, sv.z, sv.w};
#pragma unroll
        for (int e = 0; e < 4; ++e) {
            unsigned u = __float_as_uint(ss[e]);
            unsigned m = (u & 0x80000000u) ? ~u : (u | 0x80000000u);
            v[e] = ((uint64_t)m << 32) | (unsigned)(base + e);
            myv += (ss[e] > 0.05f) ? 1 : 0;
        }
    }
    for (int off = 32; off; off >>= 1) myv += __shfl_down(myv, off, 64);
    if (lane == 0) atomicAdd(&nvalid_sh, myv);

    // ---- phase 2: hybrid bitonic sort, descending on (mapped_score, index)
    // i bits: [1:0]=e (register), [7:2]=lane (shfl_xor), [11:8]=wave (LDS)
    for (int k = 2; k <= NN; k <<= 1) {
        for (int j = k >> 1; j >= 1; j >>= 1) {
            if (j >= 256) {
                __syncthreads();   // WAR: prior partner reads must complete
                ((uint4*)khi)[tid] = make_uint4((uint32_t)(v[0] >> 32), (uint32_t)(v[1] >> 32),
                                                (uint32_t)(v[2] >> 32), (uint32_t)(v[3] >> 32));
                ((uint4*)klo)[tid] = make_uint4((uint32_t)v[0], (uint32_t)v[1],
                                                (uint32_t)v[2], (uint32_t)v[3]);
                __syncthreads();
                int pt = tid ^ (j >> 2);
                uint4 ph = ((uint4*)khi)[pt];
                uint4 pl = ((uint4*)klo)[pt];
                uint64_t w[4];
                w[0] = ((uint64_t)ph.x << 32) | pl.x;
                w[1] = ((uint64_t)ph.y << 32) | pl.y;
                w[2] = ((uint64_t)ph.z << 32) | pl.z;
                w[3] = ((uint64_t)ph.w << 32) | pl.w;
                bool low  = ((tid & (j >> 2)) == 0);
                bool desc = ((base & k) == 0);
                bool keepmax = (low == desc);
#pragma unroll
                for (int e = 0; e < 4; ++e) {
                    uint64_t a = v[e], c = w[e];
                    v[e] = keepmax ? (a > c ? a : c) : (a < c ? a : c);
                }
            } else if (j >= 4) {
                int m = j >> 2;
                bool low  = ((lane & m) == 0);
                bool desc = ((base & k) == 0);
                bool keepmax = (low == desc);
#pragma unroll
                for (int e = 0; e < 4; ++e) {
                    uint64_t w = __shfl_xor((unsigned long long)v[e], m, 64);
                    uint64_t a = v[e];
                    v[e] = keepmax ? (a > w ? a : w) : (a < w ? a : w);
                }
            } else if (j == 2) {
                bool desc = ((base & k) == 0);   // k>=4 here: uniform over e
                ce64(v[0], v[2], desc);
                ce64(v[1], v[3], desc);
            } else { // j == 1
                bool d0 = (((base + 0) & k) == 0);
                bool d2 = (((base + 2) & k) == 0);
                ce64(v[0], v[1], d0);
                ce64(v[2], v[3], d2);
            }
        }
    }

    // ---- phase 3: write order, gather classes
#pragma unroll
    for (int e = 0; e < 4; ++e)
        order_[base + e] = (unsigned short)(v[e] & 0xFFFFu);
    __syncthreads();

    const int nvalid = nvalid_sh;  // valid boxes form a prefix of sorted order

    for (int p = tid; p < NN; p += NTH)
        clsb[p] = (unsigned char)classes[bN + order_[p]];
    __syncthreads();

    // ---- phase 4: stable class-major grouping via per-chunk ballots
    unsigned short* ccount = (unsigned short*)khi;   // [NCLS][64] overlay (10 KB)
    uint64_t mymask[4];
    int      myc[4];
#pragma unroll
    for (int r = 0; r < 4; ++r) {
        int ch = (wv << 2) + r;
        int p  = (ch << 6) + lane;
        int c  = (p < nvalid) ? (int)clsb[p] : 999;
        myc[r] = c;
        uint64_t mm = 0;
        for (int c0 = 0; c0 < NCLS; ++c0) {
            uint64_t m = __ballot(c == c0);
            if (c == c0) mm = m;
            if (lane == (c0 & 63)) ccount[c0 * 64 + ch] = (unsigned short)__popcll(m);
        }
        mymask[r] = mm;
    }
    __syncthreads();
    if (tid < NCLS) {
        int run = 0;
        for (int ch = 0; ch < 64; ++ch) {
            int t = ccount[tid * 64 + ch];
            ccount[tid * 64 + ch] = (unsigned short)run;
            run += t;
        }
        ctot[tid] = run;
    }
    __syncthreads();
    if (tid == 0) {
        int run = 0;
        for (int c = 0; c < NCLS; ++c) { cbase[c] = run; run += ctot[c]; }
        cbase[NCLS] = run;
    }
    __syncthreads();
#pragma unroll
    for (int r = 0; r < 4; ++r) {
        int ch = (wv << 2) + r;
        int p  = (ch << 6) + lane;
        if (p < nvalid) {
            int c   = myc[r];
            int rk  = __popcll(mymask[r] & ((1ull << lane) - 1ull));
            int dst = cbase[c] + (int)ccount[c * 64 + ch] + rk;
            grouped[dst] = (unsigned short)p;
        }
    }
    __syncthreads();

    // ---- phase 5: per-class greedy NMS; wave wv handles classes wv, wv+16, ...
    for (int c = wv; c < NCLS; c += 16) {
        int cb = cbase[c];
        int nc = cbase[c + 1] - cb;
        if (nc <= 0) continue;

        int nreg = nc < 256 ? nc : 256;
        int pos0 = 0, pos1 = 0, pos2 = 0, pos3 = 0;
        float4 bx0 = make_float4(0, 0, 0, 0), bx1 = bx0, bx2 = bx0, bx3 = bx0;
        {
            int m = lane;
            if (m < nreg) { pos0 = grouped[cb + m]; bx0 = boxes4[bN + order_[pos0]]; }
            m = 64 + lane;
            if (m < nreg) { pos1 = grouped[cb + m]; bx1 = boxes4[bN + order_[pos1]]; }
            m = 128 + lane;
            if (m < nreg) { pos2 = grouped[cb + m]; bx2 = boxes4[bN + order_[pos2]]; }
            m = 192 + lane;
            if (m < nreg) { pos3 = grouped[cb + m]; bx3 = boxes4[bN + order_[pos3]]; }
        }

        uint64_t supp = 0;  // bit j: member (j*64 + lane) suppressed
        for (int t = 0; t < nc; ++t) {
            int jt = t >> 6, lt = t & 63;
            uint64_t am = __ballot(((supp >> jt) & 1ull) == 0);
            if (!((am >> lt) & 1ull)) continue;   // t already suppressed

            // t is kept: record it (lane 0) and fetch its box (uniform)
            int pt;
            float t0, t1, t2, t3;
            if (jt < 4) {
                int psel  = (jt == 0) ? pos0 : (jt == 1) ? pos1 : (jt == 2) ? pos2 : pos3;
                float4 sr = (jt == 0) ? bx0  : (jt == 1) ? bx1  : (jt == 2) ? bx2  : bx3;
                pt = __shfl(psel, lt);
                t0 = __shfl(sr.x, lt);
                t1 = __shfl(sr.y, lt);
                t2 = __shfl(sr.z, lt);
                t3 = __shfl(sr.w, lt);
            } else {
                pt = grouped[cb + t];
                float4 g = boxes4[bN + order_[pt]];
                t0 = g.x; t1 = g.y; t2 = g.z; t3 = g.w;
            }
            if (lane == 0)
                atomicOr(&kwords[pt >> 6], 1ull << (pt & 63));

            float tarea;
            {
#pragma clang fp contract(off)
                tarea = (t2 - t0) * (t3 - t1);
            }

            int jmax = (nc + 63) >> 6;
            for (int j = jt; j < jmax; ++j) {
                int m = (j << 6) + lane;
                if (m <= t || m >= nc) continue;
                if ((supp >> j) & 1ull) continue;
                float c0, c1, c2, c3;
                if (j < 4) {
                    float4 sr = (j == 0) ? bx0 : (j == 1) ? bx1 : (j == 2) ? bx2 : bx3;
                    c0 = sr.x; c1 = sr.y; c2 = sr.z; c3 = sr.w;
                } else {
                    float4 g = boxes4[bN + order_[grouped[cb + m]]];
                    c0 = g.x; c1 = g.y; c2 = g.z; c3 = g.w;
                }
                if (iou_gt(c0, c1, c2, c3, t0, t1, t2, t3, tarea))
                    supp |= (1ull << j);
            }
        }
    }
    __syncthreads();

    // ---- phase 6: rank kept boxes (wave prefix over mask words) and scatter
    if (tid < 64) {
        uint64_t wd = kwords[tid];
        int cnt = __popcll(wd);
        int inc = cnt;
        for (int off = 1; off < 64; off <<= 1) {
            int t = __shfl_up(inc, off, 64);
            if (lane >= off) inc += t;
        }
        woff[tid] = inc - cnt;
        if (tid == 63) total_sh = inc;
    }
    __syncthreads();
    int ndet = total_sh < MAXDET ? total_sh : MAXDET;
    for (int p = tid; p < NN; p += NTH) {
        uint64_t wd = kwords[p >> 6];
        if (!((wd >> (p & 63)) & 1ull)) continue;
        int rank = woff[p >> 6] + __popcll(wd & ((1ull << (p & 63)) - 1ull));
        if (rank >= MAXDET) continue;
        int orig = order_[p];
        out[OFF_SCR + b * MAXDET + rank] = scores[bN + orig];
        float4 g = boxes4[bN + orig];
        int ob = OFF_BOX + (b * MAXDET + rank) * 4;
        out[ob + 0] = g.x; out[ob + 1] = g.y;
        out[ob + 2] = g.z; out[ob + 3] = g.w;
        out[OFF_CLS + b * MAXDET + rank] = (float)clsb[p];
    }
    if (tid == 0) out[OFF_NDT + b] = (float)ndet;
}

extern "C" void kernel_launch(void* const* d_in, const int* in_sizes, int n_in,
                              void* d_out, int out_size, void* d_ws, size_t ws_size,
                              hipStream_t stream)
{
    const float* scores  = (const float*)d_in[0];
    const float* boxes   = (const float*)d_in[1];
    const int*   classes = (const int*)d_in[2];
    float*       out     = (float*)d_out;
    hipLaunchKernelGGL(nms_kernel, dim3(NB), dim3(NTH), 0, stream,
                       scores, boxes, classes, out);
}

// Round 3
// 129.858 us; speedup vs baseline: 2.8121x; 2.4882x over previous
//
#include <hip/hip_runtime.h>
#include <cstdint>

// Problem constants (fixed by reference)
#define NB      8
#define NN      4096
#define NCLS    80
#define MAXDET  300

// Output float layout (flat, 16808 elements)
#define OFF_IDX  0
#define OFF_SCR  2400
#define OFF_BOX  4800
#define OFF_CLS  14400
#define OFF_NDT  16800

// Workspace layout (bytes)
#define WS_ORDER 0                        // u16 [NB][NN]
#define WS_CLSB  (NB * NN * 2)            // u8  [NB][NN]
#define WS_KW    (NB * NN * 3)            // u64 [NB][64]   (98304, 8-aligned)
#define WS_NV    (WS_KW + NB * 64 * 8)    // i32 [NB]

// IoU > thr test, matching reference arithmetic exactly (no FMA contraction).
// c* = current (later/lower-score) box, t* = kept candidate box, tarea = its area.
__device__ __forceinline__ bool iou_gt(float c0, float c1, float c2, float c3,
                                       float t0, float t1, float t2, float t3,
                                       float tarea)
{
#pragma clang fp contract(off)
    float xx1 = fmaxf(c0, t0);
    float yy1 = fmaxf(c1, t1);
    float xx2 = fminf(c2, t2);
    float yy2 = fminf(c3, t3);
    float w = xx2 - xx1; w = fmaxf(w, 0.0f);
    float h = yy2 - yy1; h = fmaxf(h, 0.0f);
    float inter = w * h;
    float areac = (c2 - c0) * (c3 - c1);
    float uni = areac + tarea - inter;   // area_current + area_kept - inter (ref order)
    return (inter / uni) > 0.65f;
}

__device__ __forceinline__ void ce64(uint64_t& a, uint64_t& b, bool desc)
{
    uint64_t lo = (a < b) ? a : b;
    uint64_t hi = (a < b) ? b : a;
    a = desc ? hi : lo;
    b = desc ? lo : hi;
}

// ============================ K1: per-batch sort ============================
__global__ __launch_bounds__(1024)
void k1_sort(const float* __restrict__ scores,
             const int*   __restrict__ classes,
             unsigned short* __restrict__ order_g,
             unsigned char*  __restrict__ clsb_g,
             uint64_t*       __restrict__ kwords_g,
             int*            __restrict__ nvalid_g)
{
    const int b    = blockIdx.x;
    const int tid  = threadIdx.x;
    const int lane = tid & 63;

    __shared__ __align__(16) uint32_t khi[NN];   // 16 KB
    __shared__ __align__(16) uint32_t klo[NN];   // 16 KB
    __shared__ int nvalid_sh;

    const int bN = b * NN;
    if (tid == 0) nvalid_sh = 0;
    if (tid < 64) kwords_g[b * 64 + tid] = 0;
    __syncthreads();

    // keys in registers, 4 elements/thread: i = tid*4 + e
    const int base = tid << 2;
    uint64_t v[4];
    int myv = 0;
    {
        const float4* s4 = reinterpret_cast<const float4*>(scores + bN);
        float4 sv = s4[tid];
        float ss[4] = {sv.x, sv.y, sv.z, sv.w};
#pragma unroll
        for (int e = 0; e < 4; ++e) {
            unsigned u = __float_as_uint(ss[e]);
            unsigned m = (u & 0x80000000u) ? ~u : (u | 0x80000000u);
            v[e] = ((uint64_t)m << 32) | (unsigned)(base + e);
            myv += (ss[e] > 0.05f) ? 1 : 0;
        }
    }
    for (int off = 32; off; off >>= 1) myv += __shfl_down(myv, off, 64);
    if (lane == 0) atomicAdd(&nvalid_sh, myv);

    // hybrid bitonic sort, descending on (mapped_score, index)
    for (int k = 2; k <= NN; k <<= 1) {
        for (int j = k >> 1; j >= 1; j >>= 1) {
            if (j >= 256) {
                __syncthreads();
                ((uint4*)khi)[tid] = make_uint4((uint32_t)(v[0] >> 32), (uint32_t)(v[1] >> 32),
                                                (uint32_t)(v[2] >> 32), (uint32_t)(v[3] >> 32));
                ((uint4*)klo)[tid] = make_uint4((uint32_t)v[0], (uint32_t)v[1],
                                                (uint32_t)v[2], (uint32_t)v[3]);
                __syncthreads();
                int pt = tid ^ (j >> 2);
                uint4 ph = ((uint4*)khi)[pt];
                uint4 pl = ((uint4*)klo)[pt];
                uint64_t w[4];
                w[0] = ((uint64_t)ph.x << 32) | pl.x;
                w[1] = ((uint64_t)ph.y << 32) | pl.y;
                w[2] = ((uint64_t)ph.z << 32) | pl.z;
                w[3] = ((uint64_t)ph.w << 32) | pl.w;
                bool low  = ((tid & (j >> 2)) == 0);
                bool desc = ((base & k) == 0);
                bool keepmax = (low == desc);
#pragma unroll
                for (int e = 0; e < 4; ++e) {
                    uint64_t a = v[e], c = w[e];
                    v[e] = keepmax ? (a > c ? a : c) : (a < c ? a : c);
                }
            } else if (j >= 4) {
                int m = j >> 2;
                bool low  = ((lane & m) == 0);
                bool desc = ((base & k) == 0);
                bool keepmax = (low == desc);
#pragma unroll
                for (int e = 0; e < 4; ++e) {
                    uint64_t w = __shfl_xor((unsigned long long)v[e], m, 64);
                    uint64_t a = v[e];
                    v[e] = keepmax ? (a > w ? a : w) : (a < w ? a : w);
                }
            } else if (j == 2) {
                bool desc = ((base & k) == 0);
                ce64(v[0], v[2], desc);
                ce64(v[1], v[3], desc);
            } else {
                bool d0 = (((base + 0) & k) == 0);
                bool d2 = (((base + 2) & k) == 0);
                ce64(v[0], v[1], d0);
                ce64(v[2], v[3], d2);
            }
        }
    }

    // write order + gathered class directly from registers
#pragma unroll
    for (int e = 0; e < 4; ++e) {
        int orig = (int)(v[e] & 0xFFFFu);
        order_g[bN + base + e] = (unsigned short)orig;
        clsb_g[bN + base + e]  = (unsigned char)classes[bN + orig];
    }
    if (tid == 0) nvalid_g[b] = nvalid_sh;
}

// ===================== K2: per-(batch,class) greedy NMS =====================
__global__ __launch_bounds__(64)
void k2_nms(const float* __restrict__ boxes,
            const unsigned short* __restrict__ order_g,
            const unsigned char*  __restrict__ clsb_g,
            uint64_t*             __restrict__ kwords_g,
            const int*            __restrict__ nvalid_g)
{
    const int bc   = blockIdx.x;
    const int b    = bc / NCLS;
    const int c    = bc - b * NCLS;
    const int lane = threadIdx.x;
    const int bN   = b * NN;

    __shared__ unsigned short mem[NN];   // member positions (sorted order), 8 KB

    const unsigned char* clsb = clsb_g + bN;
    const float4* boxes4 = reinterpret_cast<const float4*>(boxes);
    const int nvalid = nvalid_g[b];

    // gather members of class c among valid prefix, preserving sorted order
    int nc = 0;
    const uint64_t lmask = (1ull << lane) - 1ull;
    const int nch = (nvalid + 63) >> 6;
    for (int ch = 0; ch < nch; ++ch) {
        int p = (ch << 6) + lane;
        bool sel = (p < nvalid) && ((int)clsb[p] == c);
        uint64_t mk = __ballot(sel);
        if (sel) mem[nc + __popcll(mk & lmask)] = (unsigned short)p;
        nc += (int)__popcll(mk);
    }
    __syncthreads();
    if (nc <= 0) return;

    if (nc <= 64) {
        // ---- fast path: all members in one chunk
        float4 bx = make_float4(0, 0, 0, 0);
        float  area = 0.0f;
        if (lane < nc) {
            int pos  = mem[lane];
            int orig = order_g[bN + pos];
            bx = boxes4[bN + orig];
            {
#pragma clang fp contract(off)
                area = (bx.z - bx.x) * (bx.w - bx.y);
            }
        }
        // pairwise overlap bits vs earlier members (wave-parallel, no serial chain)
        uint64_t ov = 0;
        for (int j = 0; j < nc - 1; ++j) {
            float t0 = __shfl(bx.x, j), t1 = __shfl(bx.y, j);
            float t2 = __shfl(bx.z, j), t3 = __shfl(bx.w, j);
            float ta = __shfl(area, j);
            if (lane > j && lane < nc &&
                iou_gt(bx.x, bx.y, bx.z, bx.w, t0, t1, t2, t3, ta))
                ov |= 1ull << j;
        }
        // greedy resolution: scalar mask dance
        uint64_t alive = (nc >= 64) ? ~0ull : ((1ull << nc) - 1ull);
        for (int t = 0; t < nc; ++t) {
            if (!((alive >> t) & 1ull)) continue;
            uint64_t die = __ballot(((ov >> t) & 1ull) != 0);
            alive &= ~die;
        }
        if (lane < nc && ((alive >> lane) & 1ull)) {
            int pos = mem[lane];
            atomicOr(&kwords_g[b * 64 + (pos >> 6)], 1ull << (pos & 63));
        }
    } else if (nc <= 128) {
        // ---- medium path: two chunks per lane
        const int mB = 64 + lane;
        float4 bA = make_float4(0, 0, 0, 0), bB = bA;
        float  aA = 0.0f, aB = 0.0f;
        if (lane < nc) {
            int orig = order_g[bN + mem[lane]];
            bA = boxes4[bN + orig];
            {
#pragma clang fp contract(off)
                aA = (bA.z - bA.x) * (bA.w - bA.y);
            }
        }
        if (mB < nc) {
            int orig = order_g[bN + mem[mB]];
            bB = boxes4[bN + orig];
            {
#pragma clang fp contract(off)
                aB = (bB.z - bB.x) * (bB.w - bB.y);
            }
        }
        uint64_t ovA0 = 0, ovB0 = 0, ovB1 = 0;
        for (int j = 0; j < nc - 1; ++j) {
            float t0, t1, t2, t3, ta;
            if (j < 64) {
                t0 = __shfl(bA.x, j); t1 = __shfl(bA.y, j);
                t2 = __shfl(bA.z, j); t3 = __shfl(bA.w, j);
                ta = __shfl(aA, j);
                if (lane > j && lane < nc &&
                    iou_gt(bA.x, bA.y, bA.z, bA.w, t0, t1, t2, t3, ta))
                    ovA0 |= 1ull << j;
                if (mB < nc &&
                    iou_gt(bB.x, bB.y, bB.z, bB.w, t0, t1, t2, t3, ta))
                    ovB0 |= 1ull << j;
            } else {
                int jj = j - 64;
                t0 = __shfl(bB.x, jj); t1 = __shfl(bB.y, jj);
                t2 = __shfl(bB.z, jj); t3 = __shfl(bB.w, jj);
                ta = __shfl(aB, jj);
                if (mB > j && mB < nc &&
                    iou_gt(bB.x, bB.y, bB.z, bB.w, t0, t1, t2, t3, ta))
                    ovB1 |= 1ull << jj;
            }
        }
        uint64_t alive0 = (nc >= 64) ? ~0ull : ((1ull << nc) - 1ull);
        uint64_t alive1 = (nc >= 128) ? ~0ull : ((1ull << (nc - 64)) - 1ull);
        for (int t = 0; t < nc; ++t) {
            if (t < 64) {
                if (!((alive0 >> t) & 1ull)) continue;
                uint64_t d0 = __ballot(((ovA0 >> t) & 1ull) != 0);
                uint64_t d1 = __ballot(((ovB0 >> t) & 1ull) != 0);
                alive0 &= ~d0;
                alive1 &= ~d1;
            } else {
                int tt = t - 64;
                if (!((alive1 >> tt) & 1ull)) continue;
                uint64_t d1 = __ballot(((ovB1 >> tt) & 1ull) != 0);
                alive1 &= ~d1;
            }
        }
        if (lane < nc && ((alive0 >> lane) & 1ull)) {
            int pos = mem[lane];
            atomicOr(&kwords_g[b * 64 + (pos >> 6)], 1ull << (pos & 63));
        }
        if (mB < nc && ((alive1 >> lane) & 1ull)) {
            int pos = mem[mB];
            atomicOr(&kwords_g[b * 64 + (pos >> 6)], 1ull << (pos & 63));
        }
    } else {
        // ---- generic fallback (statistically never taken; correctness net)
        int nreg = nc < 256 ? nc : 256;
        float4 bx0 = make_float4(0, 0, 0, 0), bx1 = bx0, bx2 = bx0, bx3 = bx0;
        {
            int m = lane;
            if (m < nreg) bx0 = boxes4[bN + order_g[bN + mem[m]]];
            m = 64 + lane;
            if (m < nreg) bx1 = boxes4[bN + order_g[bN + mem[m]]];
            m = 128 + lane;
            if (m < nreg) bx2 = boxes4[bN + order_g[bN + mem[m]]];
            m = 192 + lane;
            if (m < nreg) bx3 = boxes4[bN + order_g[bN + mem[m]]];
        }
        uint64_t supp = 0;
        int jmaxc = (nc + 63) >> 6;
        for (int t = 0; t < nc; ++t) {
            int jt = t >> 6, lt = t & 63;
            uint64_t am = __ballot(((supp >> jt) & 1ull) == 0);
            if (!((am >> lt) & 1ull)) continue;

            int pt = mem[t];
            float t0, t1, t2, t3;
            if (jt < 4) {
                float4 sr = (jt == 0) ? bx0 : (jt == 1) ? bx1 : (jt == 2) ? bx2 : bx3;
                t0 = __shfl(sr.x, lt); t1 = __shfl(sr.y, lt);
                t2 = __shfl(sr.z, lt); t3 = __shfl(sr.w, lt);
            } else {
                float4 g = boxes4[bN + order_g[bN + pt]];
                t0 = g.x; t1 = g.y; t2 = g.z; t3 = g.w;
            }
            if (lane == 0)
                atomicOr(&kwords_g[b * 64 + (pt >> 6)], 1ull << (pt & 63));
            float tarea;
            {
#pragma clang fp contract(off)
                tarea = (t2 - t0) * (t3 - t1);
            }
            for (int j = jt; j < jmaxc; ++j) {
                int m = (j << 6) + lane;
                if (m <= t || m >= nc) continue;
                if ((supp >> j) & 1ull) continue;
                float c0, c1, c2, c3;
                if (j < 4) {
                    float4 sr = (j == 0) ? bx0 : (j == 1) ? bx1 : (j == 2) ? bx2 : bx3;
                    c0 = sr.x; c1 = sr.y; c2 = sr.z; c3 = sr.w;
                } else {
                    float4 g = boxes4[bN + order_g[bN + mem[m]]];
                    c0 = g.x; c1 = g.y; c2 = g.z; c3 = g.w;
                }
                if (iou_gt(c0, c1, c2, c3, t0, t1, t2, t3, tarea))
                    supp |= (1ull << j);
            }
        }
    }
}

// ======================= K3: per-batch pack + output ========================
__global__ __launch_bounds__(256)
void k3_pack(const float* __restrict__ scores,
             const float* __restrict__ boxes,
             const unsigned short* __restrict__ order_g,
             const unsigned char*  __restrict__ clsb_g,
             const uint64_t*       __restrict__ kwords_g,
             float* __restrict__ out)
{
    const int b    = blockIdx.x;
    const int tid  = threadIdx.x;
    const int lane = tid & 63;
    const int bN   = b * NN;

    __shared__ uint64_t kw[64];
    __shared__ int      woff[64];
    __shared__ int      total_sh;

    // static fills (harness poisons d_out before every timed replay)
    for (int s = tid; s < MAXDET; s += 256) {
        out[OFF_IDX + b * MAXDET + s] = -1.0f;
        out[OFF_SCR + b * MAXDET + s] = 0.0f;
        int ob = OFF_BOX + (b * MAXDET + s) * 4;
        out[ob + 0] = 0.0f; out[ob + 1] = 0.0f;
        out[ob + 2] = 0.0f; out[ob + 3] = 0.0f;
        out[OFF_CLS + b * MAXDET + s] = 0.0f;
    }

    if (tid < 64) {
        uint64_t wd = kwords_g[b * 64 + tid];
        kw[tid] = wd;
        int cnt = __popcll(wd);
        int inc = cnt;
        for (int off = 1; off < 64; off <<= 1) {
            int t = __shfl_up(inc, off, 64);
            if (lane >= off) inc += t;
        }
        woff[tid] = inc - cnt;
        if (tid == 63) total_sh = inc;
    }
    __syncthreads();

    const float4* boxes4 = reinterpret_cast<const float4*>(boxes);
    int ndet = total_sh < MAXDET ? total_sh : MAXDET;
    for (int p = tid; p < NN; p += 256) {
        uint64_t wd = kw[p >> 6];
        if (!((wd >> (p & 63)) & 1ull)) continue;
        int rank = woff[p >> 6] + __popcll(wd & ((1ull << (p & 63)) - 1ull));
        if (rank >= MAXDET) continue;
        int orig = order_g[bN + p];
        out[OFF_SCR + b * MAXDET + rank] = scores[bN + orig];
        float4 g = boxes4[bN + orig];
        int ob = OFF_BOX + (b * MAXDET + rank) * 4;
        out[ob + 0] = g.x; out[ob + 1] = g.y;
        out[ob + 2] = g.z; out[ob + 3] = g.w;
        out[OFF_CLS + b * MAXDET + rank] = (float)clsb_g[bN + p];
    }
    if (tid == 0) out[OFF_NDT + b] = (float)ndet;
}

extern "C" void kernel_launch(void* const* d_in, const int* in_sizes, int n_in,
                              void* d_out, int out_size, void* d_ws, size_t ws_size,
                              hipStream_t stream)
{
    const float* scores  = (const float*)d_in[0];
    const float* boxes   = (const float*)d_in[1];
    const int*   classes = (const int*)d_in[2];
    float*       out     = (float*)d_out;

    char* ws = (char*)d_ws;
    unsigned short* order_g  = (unsigned short*)(ws + WS_ORDER);
    unsigned char*  clsb_g   = (unsigned char*)(ws + WS_CLSB);
    uint64_t*       kwords_g = (uint64_t*)(ws + WS_KW);
    int*            nvalid_g = (int*)(ws + WS_NV);

    hipLaunchKernelGGL(k1_sort, dim3(NB), dim3(1024), 0, stream,
                       scores, classes, order_g, clsb_g, kwords_g, nvalid_g);
    hipLaunchKernelGGL(k2_nms, dim3(NB * NCLS), dim3(64), 0, stream,
                       boxes, order_g, clsb_g, kwords_g, nvalid_g);
    hipLaunchKernelGGL(k3_pack, dim3(NB), dim3(256), 0, stream,
                       scores, boxes, order_g, clsb_g, kwords_g, out);
}

// Round 4
// 118.309 us; speedup vs baseline: 3.0867x; 1.0976x over previous
//
#include <hip/hip_runtime.h>
#include <cstdint>

// Problem constants (fixed by reference)
#define NB      8
#define NN      4096
#define NCLS    80
#define MAXDET  300

// Output float layout (flat, 16808 elements)
#define OFF_IDX  0
#define OFF_SCR  2400
#define OFF_BOX  4800
#define OFF_CLS  14400
#define OFF_NDT  16800

// Workspace layout (bytes)
#define WS_ORDER 0                                  // u16 [NB][NN]
#define WS_CLSB  (NB * NN * 2)                      // u8  [NB][NN]
#define WS_GROUP (NB * NN * 3)                      // u16 [NB][NN] class-major positions
#define WS_CBASE (NB * NN * 5)                      // i32 [NB][NCLS+1]
#define WS_KW    (WS_CBASE + NB * (NCLS + 1) * 4)   // u64 [NB][64]

// IoU > thr test, matching reference arithmetic exactly (no FMA contraction).
__device__ __forceinline__ bool iou_gt(float c0, float c1, float c2, float c3,
                                       float t0, float t1, float t2, float t3,
                                       float tarea)
{
#pragma clang fp contract(off)
    float xx1 = fmaxf(c0, t0);
    float yy1 = fmaxf(c1, t1);
    float xx2 = fminf(c2, t2);
    float yy2 = fminf(c3, t3);
    float w = xx2 - xx1; w = fmaxf(w, 0.0f);
    float h = yy2 - yy1; h = fmaxf(h, 0.0f);
    float inter = w * h;
    float areac = (c2 - c0) * (c3 - c1);
    float uni = areac + tarea - inter;
    return (inter / uni) > 0.65f;
}

__device__ __forceinline__ void ce64(uint64_t& a, uint64_t& b, bool desc)
{
    uint64_t lo = (a < b) ? a : b;
    uint64_t hi = (a < b) ? b : a;
    a = desc ? hi : lo;
    b = desc ? lo : hi;
}

__device__ __forceinline__ uint64_t shfl_xor64(uint64_t x, int m)
{
    unsigned lo = __shfl_xor((unsigned)x, m, 64);
    unsigned hi = __shfl_xor((unsigned)(x >> 32), m, 64);
    return ((uint64_t)hi << 32) | lo;
}

// ================= K1: per-batch sort (256 thr x 16 elem) + grouping ========
// i-bit layout: [3:0]=e (register), [9:4]=lane (shfl), [11:10]=wave (LDS)
__global__ __launch_bounds__(256)
void k1_sort(const float* __restrict__ scores,
             const int*   __restrict__ classes,
             unsigned short* __restrict__ order_g,
             unsigned char*  __restrict__ clsb_g,
             unsigned short* __restrict__ grouped_g,
             int*            __restrict__ cbase_g,
             uint64_t*       __restrict__ kwords_g)
{
    const int b    = blockIdx.x;
    const int tid  = threadIdx.x;
    const int lane = tid & 63;
    const int wv   = tid >> 6;          // 0..3
    const int B    = tid << 4;          // this thread's 16-element base index
    const int bN   = b * NN;

    __shared__ uint64_t keys_s[NN];     // 32 KB (used only for j>=1024 stages)
    __shared__ int ccnt_s[NCLS];
    __shared__ int coff_s[NCLS];
    __shared__ int cbase_s[NCLS + 1];
    __shared__ int nvalid_sh;

    if (tid == 0) nvalid_sh = 0;
    if (tid < 64) kwords_g[b * 64 + tid] = 0;
    if (tid < NCLS) ccnt_s[tid] = 0;
    __syncthreads();

    // ---- load 16 scores, build u64 keys (mapped_score<<32 | index)
    uint64_t v[16];
    int myv = 0;
    {
        const float4* s4 = reinterpret_cast<const float4*>(scores + bN);
#pragma unroll
        for (int q = 0; q < 4; ++q) {
            float4 sv = s4[tid * 4 + q];
            float ss[4] = {sv.x, sv.y, sv.z, sv.w};
#pragma unroll
            for (int r = 0; r < 4; ++r) {
                int e = q * 4 + r;
                unsigned u = __float_as_uint(ss[r]);
                unsigned m = (u & 0x80000000u) ? ~u : (u | 0x80000000u);
                v[e] = ((uint64_t)m << 32) | (unsigned)(B + e);
                myv += (ss[r] > 0.05f) ? 1 : 0;
            }
        }
    }
    for (int off = 32; off; off >>= 1) myv += __shfl_down(myv, off, 64);
    if (lane == 0) atomicAdd(&nvalid_sh, myv);

    // ---- bitonic sort, descending. k=2,4,8 purely in-register:
#pragma unroll
    for (int e = 0; e < 16; e += 2) ce64(v[e], v[e + 1], ((e & 2) == 0));   // k=2
#pragma unroll
    for (int e = 0; e < 16; ++e) if (!(e & 2)) ce64(v[e], v[e | 2], ((e & 4) == 0)); // k=4 j=2
#pragma unroll
    for (int e = 0; e < 16; e += 2) ce64(v[e], v[e + 1], ((e & 4) == 0));   // k=4 j=1
#pragma unroll
    for (int e = 0; e < 16; ++e) if (!(e & 4)) ce64(v[e], v[e | 4], ((e & 8) == 0)); // k=8 j=4
#pragma unroll
    for (int e = 0; e < 16; ++e) if (!(e & 2)) ce64(v[e], v[e | 2], ((e & 8) == 0)); // k=8 j=2
#pragma unroll
    for (int e = 0; e < 16; e += 2) ce64(v[e], v[e + 1], ((e & 8) == 0));   // k=8 j=1

    const int s = lane & 15;   // LDS address swizzle
    for (int k = 16; k <= NN; k <<= 1) {
        bool d;
        if (k <= 512)       d = ((lane & (k >> 4)) == 0);
        else if (k == 1024) d = ((wv & 1) == 0);
        else if (k == 2048) d = ((wv & 2) == 0);
        else                d = true;

        // LDS stages (j >= 1024): exchange across waves
        for (int j = k >> 1; j >= 1024; j >>= 1) {
            __syncthreads();
#pragma unroll
            for (int t = 0; t < 16; ++t) keys_s[B + (t ^ s)] = v[t];
            __syncthreads();
            const int pb = B ^ j;
            const bool keepmax = (((B & j) == 0) == d);
#pragma unroll
            for (int e = 0; e < 16; ++e) {
                uint64_t w = keys_s[pb + (e ^ s)];
                uint64_t a = v[e];
                v[e] = keepmax ? (a > w ? a : w) : (a < w ? a : w);
            }
        }
        // shfl stages (16 <= j <= 512): exchange across lanes
        for (int j = (k >> 1) < 512 ? (k >> 1) : 512; j >= 16; j >>= 1) {
            const int m = j >> 4;
            const bool keepmax = (((lane & m) == 0) == d);
#pragma unroll
            for (int e = 0; e < 16; ++e) {
                uint64_t w = shfl_xor64(v[e], m);
                uint64_t a = v[e];
                v[e] = keepmax ? (a > w ? a : w) : (a < w ? a : w);
            }
        }
        // in-register tail (j = 8..1), direction uniform over e for k>=16
#pragma unroll
        for (int j = 8; j >= 1; j >>= 1)
#pragma unroll
            for (int e = 0; e < 16; ++e)
                if (!(e & j)) ce64(v[e], v[e | j], d);
    }

    // ---- write order (packed u64) + gather classes + write clsb (packed)
    unsigned ordv[16];
#pragma unroll
    for (int e = 0; e < 16; ++e) ordv[e] = (unsigned)(v[e] & 0xFFFFu);
    {
        uint64_t* og = (uint64_t*)(order_g + bN);
#pragma unroll
        for (int q = 0; q < 4; ++q)
            og[tid * 4 + q] = (uint64_t)ordv[4 * q]
                            | ((uint64_t)ordv[4 * q + 1] << 16)
                            | ((uint64_t)ordv[4 * q + 2] << 32)
                            | ((uint64_t)ordv[4 * q + 3] << 48);
    }
    int cls[16];
#pragma unroll
    for (int e = 0; e < 16; ++e) cls[e] = classes[bN + ordv[e]];
    {
        uint64_t* cg = (uint64_t*)(clsb_g + bN);
#pragma unroll
        for (int q = 0; q < 2; ++q) {
            uint64_t pk = 0;
#pragma unroll
            for (int r = 0; r < 8; ++r)
                pk |= ((uint64_t)(unsigned char)cls[8 * q + r]) << (8 * r);
            cg[tid * 2 + q] = pk;
        }
    }
    __syncthreads();

    // ---- class grouping (counting sort; order within class arbitrary —
    //      k2 restores score order with a tiny in-wave sort)
    const int nv = nvalid_sh;
#pragma unroll
    for (int e = 0; e < 16; ++e)
        if (B + e < nv) atomicAdd(&ccnt_s[cls[e]], 1);
    __syncthreads();
    if (tid == 0) {
        int run = 0;
        for (int c = 0; c < NCLS; ++c) {
            int t = ccnt_s[c];
            cbase_s[c] = run; coff_s[c] = run;
            run += t;
        }
        cbase_s[NCLS] = run;
    }
    __syncthreads();
#pragma unroll
    for (int e = 0; e < 16; ++e) {
        int p = B + e;
        if (p < nv) {
            int slot = atomicAdd(&coff_s[cls[e]], 1);
            grouped_g[bN + slot] = (unsigned short)p;
        }
    }
    if (tid <= NCLS) cbase_g[b * (NCLS + 1) + tid] = cbase_s[tid];
}

// ===================== K2: per-(batch,class) greedy NMS =====================
__global__ __launch_bounds__(64)
void k2_nms(const float* __restrict__ boxes,
            const unsigned short* __restrict__ order_g,
            const unsigned short* __restrict__ grouped_g,
            const int*            __restrict__ cbase_g,
            uint64_t*             __restrict__ kwords_g)
{
    const int bc   = blockIdx.x;
    const int b    = bc / NCLS;
    const int c    = bc - b * NCLS;
    const int lane = threadIdx.x;
    const int bN   = b * NN;

    __shared__ unsigned short mem[NN];   // fallback path only

    const int cb = cbase_g[b * (NCLS + 1) + c];
    const int nc = cbase_g[b * (NCLS + 1) + c + 1] - cb;
    if (nc <= 0) return;

    const float4* boxes4 = reinterpret_cast<const float4*>(boxes);

    if (nc <= 64) {
        // ---- fast path: sort 64 positions ascending (pos order == score order)
        unsigned pos = 0xFFFFFFFFu;
        if (lane < nc) pos = grouped_g[bN + cb + lane];
        for (int k = 2; k <= 64; k <<= 1) {
            bool up = ((lane & k) == 0);
            for (int j = k >> 1; j >= 1; j >>= 1) {
                unsigned w = __shfl_xor(pos, j, 64);
                bool keepmin = (((lane & j) == 0) == up);
                pos = keepmin ? (pos < w ? pos : w) : (pos > w ? pos : w);
            }
        }
        float4 bx = make_float4(0, 0, 0, 0);
        float  area = 0.0f;
        if (lane < nc) {
            int orig = order_g[bN + pos];
            bx = boxes4[bN + orig];
            {
#pragma clang fp contract(off)
                area = (bx.z - bx.x) * (bx.w - bx.y);
            }
        }
        uint64_t ov = 0;
        for (int j = 0; j < nc - 1; ++j) {
            float t0 = __shfl(bx.x, j), t1 = __shfl(bx.y, j);
            float t2 = __shfl(bx.z, j), t3 = __shfl(bx.w, j);
            float ta = __shfl(area, j);
            if (lane > j && lane < nc &&
                iou_gt(bx.x, bx.y, bx.z, bx.w, t0, t1, t2, t3, ta))
                ov |= 1ull << j;
        }
        uint64_t alive = (nc >= 64) ? ~0ull : ((1ull << nc) - 1ull);
        for (int t = 0; t < nc; ++t) {
            if (!((alive >> t) & 1ull)) continue;
            uint64_t die = __ballot(((ov >> t) & 1ull) != 0);
            alive &= ~die;
        }
        if (lane < nc && ((alive >> lane) & 1ull))
            atomicOr(&kwords_g[b * 64 + (pos >> 6)], 1ull << (pos & 63));
    } else if (nc <= 128) {
        // ---- medium path: sort 128 positions ascending; i = (e<<6)|lane
        unsigned pA = 0xFFFFFFFFu, pB = 0xFFFFFFFFu;
        if (lane < nc)      pA = grouped_g[bN + cb + lane];
        if (64 + lane < nc) pB = grouped_g[bN + cb + 64 + lane];
        for (int k = 2; k <= 128; k <<= 1) {
            bool up0 = ((lane & k) == 0);          // e=0: i=lane (k=128 -> true)
            bool up1 = (((64 | lane) & k) == 0);   // e=1
            for (int j = k >> 1; j >= 1; j >>= 1) {
                if (j == 64) {
                    unsigned mn = pA < pB ? pA : pB;
                    unsigned mx = pA < pB ? pB : pA;
                    pA = up0 ? mn : mx;
                    pB = up0 ? mx : mn;
                } else {
                    unsigned w0 = __shfl_xor(pA, j, 64);
                    bool km0 = (((lane & j) == 0) == up0);
                    pA = km0 ? (pA < w0 ? pA : w0) : (pA > w0 ? pA : w0);
                    unsigned w1 = __shfl_xor(pB, j, 64);
                    bool km1 = (((lane & j) == 0) == up1);
                    pB = km1 ? (pB < w1 ? pB : w1) : (pB > w1 ? pB : w1);
                }
            }
        }
        const int mB = 64 + lane;
        float4 bA = make_float4(0, 0, 0, 0), bB = bA;
        float  aA = 0.0f, aB = 0.0f;
        if (lane < nc) {
            bA = boxes4[bN + order_g[bN + pA]];
            {
#pragma clang fp contract(off)
                aA = (bA.z - bA.x) * (bA.w - bA.y);
            }
        }
        if (mB < nc) {
            bB = boxes4[bN + order_g[bN + pB]];
            {
#pragma clang fp contract(off)
                aB = (bB.z - bB.x) * (bB.w - bB.y);
            }
        }
        uint64_t ovA0 = 0, ovB0 = 0, ovB1 = 0;
        for (int j = 0; j < nc - 1; ++j) {
            if (j < 64) {
                float t0 = __shfl(bA.x, j), t1 = __shfl(bA.y, j);
                float t2 = __shfl(bA.z, j), t3 = __shfl(bA.w, j);
                float ta = __shfl(aA, j);
                if (lane > j && lane < nc &&
                    iou_gt(bA.x, bA.y, bA.z, bA.w, t0, t1, t2, t3, ta))
                    ovA0 |= 1ull << j;
                if (mB < nc &&
                    iou_gt(bB.x, bB.y, bB.z, bB.w, t0, t1, t2, t3, ta))
                    ovB0 |= 1ull << j;
            } else {
                int jj = j - 64;
                float t0 = __shfl(bB.x, jj), t1 = __shfl(bB.y, jj);
                float t2 = __shfl(bB.z, jj), t3 = __shfl(bB.w, jj);
                float ta = __shfl(aB, jj);
                if (mB > j && mB < nc &&
                    iou_gt(bB.x, bB.y, bB.z, bB.w, t0, t1, t2, t3, ta))
                    ovB1 |= 1ull << jj;
            }
        }
        uint64_t alive0 = (nc >= 64) ? ~0ull : ((1ull << nc) - 1ull);
        uint64_t alive1 = (nc >= 128) ? ~0ull : ((1ull << (nc - 64)) - 1ull);
        for (int t = 0; t < nc; ++t) {
            if (t < 64) {
                if (!((alive0 >> t) & 1ull)) continue;
                uint64_t d0 = __ballot(((ovA0 >> t) & 1ull) != 0);
                uint64_t d1 = __ballot(((ovB0 >> t) & 1ull) != 0);
                alive0 &= ~d0;
                alive1 &= ~d1;
            } else {
                int tt = t - 64;
                if (!((alive1 >> tt) & 1ull)) continue;
                uint64_t d1 = __ballot(((ovB1 >> tt) & 1ull) != 0);
                alive1 &= ~d1;
            }
        }
        if (lane < nc && ((alive0 >> lane) & 1ull)) {
            unsigned pos = pA;
            atomicOr(&kwords_g[b * 64 + (pos >> 6)], 1ull << (pos & 63));
        }
        if (mB < nc && ((alive1 >> lane) & 1ull)) {
            unsigned pos = pB;
            atomicOr(&kwords_g[b * 64 + (pos >> 6)], 1ull << (pos & 63));
        }
    } else {
        // ---- generic fallback (statistically never taken; correctness net)
        for (int m = lane; m < nc; m += 64) mem[m] = grouped_g[bN + cb + m];
        __syncthreads();
        // odd-even transposition sort ascending (block = single wave)
        for (int r = 0; r < nc; ++r) {
            int st = r & 1;
            for (int m = st + 2 * lane; m + 1 < nc; m += 128) {
                unsigned short x = mem[m], y = mem[m + 1];
                if (x > y) { mem[m] = y; mem[m + 1] = x; }
            }
            __syncthreads();
        }
        int nreg = nc < 256 ? nc : 256;
        float4 bx0 = make_float4(0, 0, 0, 0), bx1 = bx0, bx2 = bx0, bx3 = bx0;
        {
            int m = lane;
            if (m < nreg) bx0 = boxes4[bN + order_g[bN + mem[m]]];
            m = 64 + lane;
            if (m < nreg) bx1 = boxes4[bN + order_g[bN + mem[m]]];
            m = 128 + lane;
            if (m < nreg) bx2 = boxes4[bN + order_g[bN + mem[m]]];
            m = 192 + lane;
            if (m < nreg) bx3 = boxes4[bN + order_g[bN + mem[m]]];
        }
        uint64_t supp = 0;
        int jmaxc = (nc + 63) >> 6;
        for (int t = 0; t < nc; ++t) {
            int jt = t >> 6, lt = t & 63;
            uint64_t am = __ballot(((supp >> jt) & 1ull) == 0);
            if (!((am >> lt) & 1ull)) continue;
            int pt = mem[t];
            float t0, t1, t2, t3;
            if (jt < 4) {
                float4 sr = (jt == 0) ? bx0 : (jt == 1) ? bx1 : (jt == 2) ? bx2 : bx3;
                t0 = __shfl(sr.x, lt); t1 = __shfl(sr.y, lt);
                t2 = __shfl(sr.z, lt); t3 = __shfl(sr.w, lt);
            } else {
                float4 g = boxes4[bN + order_g[bN + pt]];
                t0 = g.x; t1 = g.y; t2 = g.z; t3 = g.w;
            }
            if (lane == 0)
                atomicOr(&kwords_g[b * 64 + (pt >> 6)], 1ull << (pt & 63));
            float tarea;
            {
#pragma clang fp contract(off)
                tarea = (t2 - t0) * (t3 - t1);
            }
            for (int j = jt; j < jmaxc; ++j) {
                int m = (j << 6) + lane;
                if (m <= t || m >= nc) continue;
                if ((supp >> j) & 1ull) continue;
                float c0, c1, c2, c3;
                if (j < 4) {
                    float4 sr = (j == 0) ? bx0 : (j == 1) ? bx1 : (j == 2) ? bx2 : bx3;
                    c0 = sr.x; c1 = sr.y; c2 = sr.z; c3 = sr.w;
                } else {
                    float4 g = boxes4[bN + order_g[bN + mem[m]]];
                    c0 = g.x; c1 = g.y; c2 = g.z; c3 = g.w;
                }
                if (iou_gt(c0, c1, c2, c3, t0, t1, t2, t3, tarea))
                    supp |= (1ull << j);
            }
        }
    }
}

// ======================= K3: per-batch pack + output ========================
__global__ __launch_bounds__(256)
void k3_pack(const float* __restrict__ scores,
             const float* __restrict__ boxes,
             const unsigned short* __restrict__ order_g,
             const unsigned char*  __restrict__ clsb_g,
             const uint64_t*       __restrict__ kwords_g,
             float* __restrict__ out)
{
    const int b    = blockIdx.x;
    const int tid  = threadIdx.x;
    const int lane = tid & 63;
    const int bN   = b * NN;

    __shared__ uint64_t kw[64];
    __shared__ int      woff[64];
    __shared__ int      total_sh;

    for (int s = tid; s < MAXDET; s += 256) {
        out[OFF_IDX + b * MAXDET + s] = -1.0f;
        out[OFF_SCR + b * MAXDET + s] = 0.0f;
        int ob = OFF_BOX + (b * MAXDET + s) * 4;
        out[ob + 0] = 0.0f; out[ob + 1] = 0.0f;
        out[ob + 2] = 0.0f; out[ob + 3] = 0.0f;
        out[OFF_CLS + b * MAXDET + s] = 0.0f;
    }

    if (tid < 64) {
        uint64_t wd = kwords_g[b * 64 + tid];
        kw[tid] = wd;
        int cnt = __popcll(wd);
        int inc = cnt;
        for (int off = 1; off < 64; off <<= 1) {
            int t = __shfl_up(inc, off, 64);
            if (lane >= off) inc += t;
        }
        woff[tid] = inc - cnt;
        if (tid == 63) total_sh = inc;
    }
    __syncthreads();

    const float4* boxes4 = reinterpret_cast<const float4*>(boxes);
    int ndet = total_sh < MAXDET ? total_sh : MAXDET;
    for (int p = tid; p < NN; p += 256) {
        uint64_t wd = kw[p >> 6];
        if (!((wd >> (p & 63)) & 1ull)) continue;
        int rank = woff[p >> 6] + __popcll(wd & ((1ull << (p & 63)) - 1ull));
        if (rank >= MAXDET) continue;
        int orig = order_g[bN + p];
        out[OFF_SCR + b * MAXDET + rank] = scores[bN + orig];
        float4 g = boxes4[bN + orig];
        int ob = OFF_BOX + (b * MAXDET + rank) * 4;
        out[ob + 0] = g.x; out[ob + 1] = g.y;
        out[ob + 2] = g.z; out[ob + 3] = g.w;
        out[OFF_CLS + b * MAXDET + rank] = (float)clsb_g[bN + p];
    }
    if (tid == 0) out[OFF_NDT + b] = (float)ndet;
}

extern "C" void kernel_launch(void* const* d_in, const int* in_sizes, int n_in,
                              void* d_out, int out_size, void* d_ws, size_t ws_size,
                              hipStream_t stream)
{
    const float* scores  = (const float*)d_in[0];
    const float* boxes   = (const float*)d_in[1];
    const int*   classes = (const int*)d_in[2];
    float*       out     = (float*)d_out;

    char* ws = (char*)d_ws;
    unsigned short* order_g   = (unsigned short*)(ws + WS_ORDER);
    unsigned char*  clsb_g    = (unsigned char*)(ws + WS_CLSB);
    unsigned short* grouped_g = (unsigned short*)(ws + WS_GROUP);
    int*            cbase_g   = (int*)(ws + WS_CBASE);
    uint64_t*       kwords_g  = (uint64_t*)(ws + WS_KW);

    hipLaunchKernelGGL(k1_sort, dim3(NB), dim3(256), 0, stream,
                       scores, classes, order_g, clsb_g, grouped_g, cbase_g, kwords_g);
    hipLaunchKernelGGL(k2_nms, dim3(NB * NCLS), dim3(64), 0, stream,
                       boxes, order_g, grouped_g, cbase_g, kwords_g);
    hipLaunchKernelGGL(k3_pack, dim3(NB), dim3(256), 0, stream,
                       scores, boxes, order_g, clsb_g, kwords_g, out);
}

// Round 5
// 113.517 us; speedup vs baseline: 3.2170x; 1.0422x over previous
//
#include <hip/hip_runtime.h>
#include <cstdint>

// Problem constants (fixed by reference)
#define NB      8
#define NN      4096
#define NCLS    80
#define MAXDET  300

// Output float layout (flat, 16808 elements)
#define OFF_IDX  0
#define OFF_SCR  2400
#define OFF_BOX  4800
#define OFF_CLS  14400
#define OFF_NDT  16800

// Workspace layout (bytes)
#define WS_ORDER 0                                  // u16 [NB][NN]
#define WS_CLSB  (NB * NN * 2)                      // u8  [NB][NN]
#define WS_GROUP (NB * NN * 3)                      // u16 [NB][NN] class-major positions
#define WS_CBASE (NB * NN * 5)                      // i32 [NB][NCLS+1]
#define WS_KW    (WS_CBASE + NB * (NCLS + 1) * 4)   // u64 [NB][64]

// IoU > thr test, matching reference arithmetic exactly (no FMA contraction).
__device__ __forceinline__ bool iou_gt(float c0, float c1, float c2, float c3,
                                       float t0, float t1, float t2, float t3,
                                       float tarea)
{
#pragma clang fp contract(off)
    float xx1 = fmaxf(c0, t0);
    float yy1 = fmaxf(c1, t1);
    float xx2 = fminf(c2, t2);
    float yy2 = fminf(c3, t3);
    float w = xx2 - xx1; w = fmaxf(w, 0.0f);
    float h = yy2 - yy1; h = fmaxf(h, 0.0f);
    float inter = w * h;
    float areac = (c2 - c0) * (c3 - c1);
    float uni = areac + tarea - inter;
    return (inter / uni) > 0.65f;
}

__device__ __forceinline__ void ce64(uint64_t& a, uint64_t& b, bool desc)
{
    uint64_t lo = (a < b) ? a : b;
    uint64_t hi = (a < b) ? b : a;
    a = desc ? hi : lo;
    b = desc ? lo : hi;
}

// ============ K1: per-batch sort (512 thr x 8 elem) + class grouping ========
// i-bit layout: [2:0]=e (register), [8:3]=lane (shfl), [11:9]=wave (LDS)
__global__ __launch_bounds__(512)
void k1_sort(const float* __restrict__ scores,
             const int*   __restrict__ classes,
             unsigned short* __restrict__ order_g,
             unsigned char*  __restrict__ clsb_g,
             unsigned short* __restrict__ grouped_g,
             int*            __restrict__ cbase_g,
             uint64_t*       __restrict__ kwords_g)
{
    const int b    = blockIdx.x;
    const int tid  = threadIdx.x;
    const int lane = tid & 63;
    const int wv   = tid >> 6;          // 0..7
    const int B    = tid << 3;          // 8-element base index
    const int bN   = b * NN;

    __shared__ uint64_t keys_s[NN];     // 32 KB (only for j>=512 stages)
    __shared__ int ccnt_s[NCLS];
    __shared__ int coff_s[NCLS];
    __shared__ int cbase_s[NCLS + 1];
    __shared__ int nvalid_sh;

    if (tid == 0) nvalid_sh = 0;
    if (tid < 64) kwords_g[b * 64 + tid] = 0;
    if (tid < NCLS) ccnt_s[tid] = 0;
    __syncthreads();

    // ---- load 8 scores, build u64 keys (mapped_score<<32 | index)
    uint64_t v[8];
    int myv = 0;
    {
        const float4* s4 = reinterpret_cast<const float4*>(scores + bN);
#pragma unroll
        for (int q = 0; q < 2; ++q) {
            float4 sv = s4[tid * 2 + q];
            float ss[4] = {sv.x, sv.y, sv.z, sv.w};
#pragma unroll
            for (int r = 0; r < 4; ++r) {
                int e = q * 4 + r;
                unsigned u = __float_as_uint(ss[r]);
                unsigned m = (u & 0x80000000u) ? ~u : (u | 0x80000000u);
                v[e] = ((uint64_t)m << 32) | (unsigned)(B + e);
                myv += (ss[r] > 0.05f) ? 1 : 0;
            }
        }
    }
    for (int off = 32; off; off >>= 1) myv += __shfl_down(myv, off, 64);
    if (lane == 0) atomicAdd(&nvalid_sh, myv);

    // ---- in-register pre-sort: k=2, k=4 (direction depends on e only)
    ce64(v[0], v[1], true);  ce64(v[2], v[3], false);
    ce64(v[4], v[5], true);  ce64(v[6], v[7], false);          // k=2
    ce64(v[0], v[2], true);  ce64(v[1], v[3], true);
    ce64(v[4], v[6], false); ce64(v[5], v[7], false);          // k=4 j=2
    ce64(v[0], v[1], true);  ce64(v[2], v[3], true);
    ce64(v[4], v[5], false); ce64(v[6], v[7], false);          // k=4 j=1

    const int s = tid & 7;   // LDS address swizzle (partner-consistent: j>=512)
    for (int k = 8; k <= NN; k <<= 1) {
        bool d;
        if (k <= 256)       d = ((lane & (k >> 3)) == 0);
        else if (k == 512)  d = ((wv & 1) == 0);
        else if (k == 1024) d = ((wv & 2) == 0);
        else if (k == 2048) d = ((wv & 4) == 0);
        else                d = true;

        // LDS stages (j >= 512): exchange across waves
        for (int j = k >> 1; j >= 512; j >>= 1) {
            __syncthreads();
#pragma unroll
            for (int e = 0; e < 8; ++e) keys_s[B + (e ^ s)] = v[e];
            __syncthreads();
            const int pb = B ^ j;
            const bool keepmax = (((B & j) == 0) == d);
            uint64_t w[8];
#pragma unroll
            for (int e = 0; e < 8; ++e) w[e] = keys_s[pb + (e ^ s)];
#pragma unroll
            for (int e = 0; e < 8; ++e) {
                uint64_t a = v[e], c = w[e];
                v[e] = keepmax ? (a > c ? a : c) : (a < c ? a : c);
            }
        }

        // shfl stages (8 <= j <= 256): BATCHED bpermutes, wait once
        for (int j = ((k >> 1) < 256 ? (k >> 1) : 256); j >= 8; j >>= 1) {
            const int m = j >> 3;
            const bool keepmax = (((lane & m) == 0) == d);
            unsigned wlo[8], whi[8];
#pragma unroll
            for (int e = 0; e < 8; ++e) wlo[e] = __shfl_xor((unsigned)v[e], m, 64);
#pragma unroll
            for (int e = 0; e < 8; ++e) whi[e] = __shfl_xor((unsigned)(v[e] >> 32), m, 64);
#pragma unroll
            for (int e = 0; e < 8; ++e) {
                uint64_t w = ((uint64_t)whi[e] << 32) | wlo[e];
                uint64_t a = v[e];
                v[e] = keepmax ? (a > w ? a : w) : (a < w ? a : w);
            }
        }

        // in-register tail (j=4,2,1; direction uniform per thread for k>=8)
        ce64(v[0], v[4], d); ce64(v[1], v[5], d);
        ce64(v[2], v[6], d); ce64(v[3], v[7], d);              // j=4
        ce64(v[0], v[2], d); ce64(v[1], v[3], d);
        ce64(v[4], v[6], d); ce64(v[5], v[7], d);              // j=2
        ce64(v[0], v[1], d); ce64(v[2], v[3], d);
        ce64(v[4], v[5], d); ce64(v[6], v[7], d);              // j=1
    }

    // ---- write order (packed u64) + gather classes + write clsb (packed)
    unsigned ordv[8];
#pragma unroll
    for (int e = 0; e < 8; ++e) ordv[e] = (unsigned)(v[e] & 0xFFFFu);
    {
        uint64_t* og = (uint64_t*)(order_g + bN);
#pragma unroll
        for (int q = 0; q < 2; ++q)
            og[tid * 2 + q] = (uint64_t)ordv[4 * q]
                            | ((uint64_t)ordv[4 * q + 1] << 16)
                            | ((uint64_t)ordv[4 * q + 2] << 32)
                            | ((uint64_t)ordv[4 * q + 3] << 48);
    }
    int cls[8];
#pragma unroll
    for (int e = 0; e < 8; ++e) cls[e] = classes[bN + ordv[e]];
    {
        uint64_t pk = 0;
#pragma unroll
        for (int r = 0; r < 8; ++r)
            pk |= ((uint64_t)(unsigned char)cls[r]) << (8 * r);
        ((uint64_t*)(clsb_g + bN))[tid] = pk;
    }
    __syncthreads();

    // ---- class grouping (counting sort; order within class arbitrary —
    //      k2 restores score order with a tiny in-wave sort)
    const int nv = nvalid_sh;
#pragma unroll
    for (int e = 0; e < 8; ++e)
        if (B + e < nv) atomicAdd(&ccnt_s[cls[e]], 1);
    __syncthreads();
    if (wv == 0) {   // parallel 80-bin exclusive prefix (wave 0)
        int c0 = (lane < NCLS) ? ccnt_s[lane] : 0;
        int c1 = (64 + lane < NCLS) ? ccnt_s[64 + lane] : 0;
        int i0 = c0, i1 = c1;
        for (int off = 1; off < 64; off <<= 1) {
            int t0 = __shfl_up(i0, off, 64);
            int t1 = __shfl_up(i1, off, 64);
            if (lane >= off) { i0 += t0; i1 += t1; }
        }
        int sum0 = __shfl(i0, 63);
        int tail = __shfl(i1, NCLS - 64 - 1);   // inclusive sum of classes 64..79
        if (lane < NCLS) {
            int bs = i0 - c0;
            cbase_s[lane] = bs; coff_s[lane] = bs;
        }
        if (64 + lane < NCLS) {
            int bs = sum0 + i1 - c1;
            cbase_s[64 + lane] = bs; coff_s[64 + lane] = bs;
        }
        if (lane == 0) cbase_s[NCLS] = sum0 + tail;
    }
    __syncthreads();
#pragma unroll
    for (int e = 0; e < 8; ++e) {
        int p = B + e;
        if (p < nv) {
            int slot = atomicAdd(&coff_s[cls[e]], 1);
            grouped_g[bN + slot] = (unsigned short)p;
        }
    }
    if (tid <= NCLS) cbase_g[b * (NCLS + 1) + tid] = cbase_s[tid];
}

// ===================== K2: per-(batch,class) greedy NMS =====================
__global__ __launch_bounds__(64)
void k2_nms(const float* __restrict__ boxes,
            const unsigned short* __restrict__ order_g,
            const unsigned short* __restrict__ grouped_g,
            const int*            __restrict__ cbase_g,
            uint64_t*             __restrict__ kwords_g)
{
    const int bc   = blockIdx.x;
    const int b    = bc / NCLS;
    const int c    = bc - b * NCLS;
    const int lane = threadIdx.x;
    const int bN   = b * NN;

    __shared__ float4 bx_s[128];         // box broadcast (fast/medium paths)
    __shared__ float  ar_s[128];
    __shared__ unsigned short mem[NN];   // fallback path only

    const int cb = cbase_g[b * (NCLS + 1) + c];
    const int nc = cbase_g[b * (NCLS + 1) + c + 1] - cb;
    if (nc <= 0) return;

    const float4* boxes4 = reinterpret_cast<const float4*>(boxes);

    if (nc <= 64) {
        // ---- fast path: sort 64 positions ascending (pos order == score order)
        unsigned pos = 0xFFFFFFFFu;
        if (lane < nc) pos = grouped_g[bN + cb + lane];
        for (int k = 2; k <= 64; k <<= 1) {
            bool up = ((lane & k) == 0);
            for (int j = k >> 1; j >= 1; j >>= 1) {
                unsigned w = __shfl_xor(pos, j, 64);
                bool keepmin = (((lane & j) == 0) == up);
                pos = keepmin ? (pos < w ? pos : w) : (pos > w ? pos : w);
            }
        }
        float4 bx = make_float4(0, 0, 0, 0);
        float  area = 0.0f;
        if (lane < nc) {
            bx = boxes4[bN + order_g[bN + pos]];
            {
#pragma clang fp contract(off)
                area = (bx.z - bx.x) * (bx.w - bx.y);
            }
        }
        bx_s[lane] = bx;
        ar_s[lane] = area;
        __syncthreads();
        // pairwise overlap bits vs earlier members: LDS broadcast reads,
        // 4x batched so loads pipeline (no serialized shfl chains)
        uint64_t ov = 0;
        for (int j0 = 0; j0 < nc - 1; j0 += 4) {
            float4 t[4]; float ta[4];
#pragma unroll
            for (int r = 0; r < 4; ++r) {
                t[r]  = bx_s[j0 + r];    // arrays are 128 deep: j0+3 <= 66 safe
                ta[r] = ar_s[j0 + r];
            }
#pragma unroll
            for (int r = 0; r < 4; ++r) {
                int j = j0 + r;
                if (j < nc - 1 && lane > j && lane < nc &&
                    iou_gt(bx.x, bx.y, bx.z, bx.w,
                           t[r].x, t[r].y, t[r].z, t[r].w, ta[r]))
                    ov |= 1ull << j;
            }
        }
        uint64_t alive = (nc >= 64) ? ~0ull : ((1ull << nc) - 1ull);
        for (int t = 0; t < nc; ++t) {
            if (!((alive >> t) & 1ull)) continue;
            uint64_t die = __ballot(((ov >> t) & 1ull) != 0);
            alive &= ~die;
        }
        if (lane < nc && ((alive >> lane) & 1ull))
            atomicOr(&kwords_g[b * 64 + (pos >> 6)], 1ull << (pos & 63));
    } else if (nc <= 128) {
        // ---- medium path: sort 128 positions ascending; i = (e<<6)|lane
        unsigned pA = 0xFFFFFFFFu, pB = 0xFFFFFFFFu;
        if (lane < nc)      pA = grouped_g[bN + cb + lane];
        if (64 + lane < nc) pB = grouped_g[bN + cb + 64 + lane];
        for (int k = 2; k <= 128; k <<= 1) {
            bool up0 = ((lane & k) == 0);
            bool up1 = (((64 | lane) & k) == 0);
            for (int j = k >> 1; j >= 1; j >>= 1) {
                if (j == 64) {
                    unsigned mn = pA < pB ? pA : pB;
                    unsigned mx = pA < pB ? pB : pA;
                    pA = up0 ? mn : mx;
                    pB = up0 ? mx : mn;
                } else {
                    unsigned w0 = __shfl_xor(pA, j, 64);
                    unsigned w1 = __shfl_xor(pB, j, 64);
                    bool km0 = (((lane & j) == 0) == up0);
                    bool km1 = (((lane & j) == 0) == up1);
                    pA = km0 ? (pA < w0 ? pA : w0) : (pA > w0 ? pA : w0);
                    pB = km1 ? (pB < w1 ? pB : w1) : (pB > w1 ? pB : w1);
                }
            }
        }
        const int mB = 64 + lane;
        float4 bA = make_float4(0, 0, 0, 0), bB = bA;
        float  aA = 0.0f, aB = 0.0f;
        if (lane < nc) {
            bA = boxes4[bN + order_g[bN + pA]];
            {
#pragma clang fp contract(off)
                aA = (bA.z - bA.x) * (bA.w - bA.y);
            }
        }
        if (mB < nc) {
            bB = boxes4[bN + order_g[bN + pB]];
            {
#pragma clang fp contract(off)
                aB = (bB.z - bB.x) * (bB.w - bB.y);
            }
        }
        bx_s[lane] = bA;      ar_s[lane] = aA;
        bx_s[64 + lane] = bB; ar_s[64 + lane] = aB;
        __syncthreads();
        uint64_t ovA0 = 0, ovB0 = 0, ovB1 = 0;
        for (int j = 0; j < nc - 1; ++j) {
            float4 t = bx_s[j];
            float ta = ar_s[j];
            if (j < 64) {
                if (lane > j && lane < nc &&
                    iou_gt(bA.x, bA.y, bA.z, bA.w, t.x, t.y, t.z, t.w, ta))
                    ovA0 |= 1ull << j;
                if (mB < nc &&
                    iou_gt(bB.x, bB.y, bB.z, bB.w, t.x, t.y, t.z, t.w, ta))
                    ovB0 |= 1ull << j;
            } else {
                if (mB > j && mB < nc &&
                    iou_gt(bB.x, bB.y, bB.z, bB.w, t.x, t.y, t.z, t.w, ta))
                    ovB1 |= 1ull << (j - 64);
            }
        }
        uint64_t alive0 = (nc >= 64) ? ~0ull : ((1ull << nc) - 1ull);
        uint64_t alive1 = (nc >= 128) ? ~0ull : ((1ull << (nc - 64)) - 1ull);
        for (int t = 0; t < nc; ++t) {
            if (t < 64) {
                if (!((alive0 >> t) & 1ull)) continue;
                uint64_t d0 = __ballot(((ovA0 >> t) & 1ull) != 0);
                uint64_t d1 = __ballot(((ovB0 >> t) & 1ull) != 0);
                alive0 &= ~d0;
                alive1 &= ~d1;
            } else {
                int tt = t - 64;
                if (!((alive1 >> tt) & 1ull)) continue;
                uint64_t d1 = __ballot(((ovB1 >> tt) & 1ull) != 0);
                alive1 &= ~d1;
            }
        }
        if (lane < nc && ((alive0 >> lane) & 1ull))
            atomicOr(&kwords_g[b * 64 + (pA >> 6)], 1ull << (pA & 63));
        if (mB < nc && ((alive1 >> lane) & 1ull))
            atomicOr(&kwords_g[b * 64 + (pB >> 6)], 1ull << (pB & 63));
    } else {
        // ---- generic fallback (statistically never taken; correctness net)
        for (int m = lane; m < nc; m += 64) mem[m] = grouped_g[bN + cb + m];
        __syncthreads();
        for (int r = 0; r < nc; ++r) {               // odd-even sort ascending
            int st = r & 1;
            for (int m = st + 2 * lane; m + 1 < nc; m += 128) {
                unsigned short x = mem[m], y = mem[m + 1];
                if (x > y) { mem[m] = y; mem[m + 1] = x; }
            }
            __syncthreads();
        }
        int nreg = nc < 256 ? nc : 256;
        float4 bx0 = make_float4(0, 0, 0, 0), bx1 = bx0, bx2 = bx0, bx3 = bx0;
        {
            int m = lane;
            if (m < nreg) bx0 = boxes4[bN + order_g[bN + mem[m]]];
            m = 64 + lane;
            if (m < nreg) bx1 = boxes4[bN + order_g[bN + mem[m]]];
            m = 128 + lane;
            if (m < nreg) bx2 = boxes4[bN + order_g[bN + mem[m]]];
            m = 192 + lane;
            if (m < nreg) bx3 = boxes4[bN + order_g[bN + mem[m]]];
        }
        uint64_t supp = 0;
        int jmaxc = (nc + 63) >> 6;
        for (int t = 0; t < nc; ++t) {
            int jt = t >> 6, lt = t & 63;
            uint64_t am = __ballot(((supp >> jt) & 1ull) == 0);
            if (!((am >> lt) & 1ull)) continue;
            int pt = mem[t];
            float t0, t1, t2, t3;
            if (jt < 4) {
                float4 sr = (jt == 0) ? bx0 : (jt == 1) ? bx1 : (jt == 2) ? bx2 : bx3;
                t0 = __shfl(sr.x, lt); t1 = __shfl(sr.y, lt);
                t2 = __shfl(sr.z, lt); t3 = __shfl(sr.w, lt);
            } else {
                float4 g = boxes4[bN + order_g[bN + pt]];
                t0 = g.x; t1 = g.y; t2 = g.z; t3 = g.w;
            }
            if (lane == 0)
                atomicOr(&kwords_g[b * 64 + (pt >> 6)], 1ull << (pt & 63));
            float tarea;
            {
#pragma clang fp contract(off)
                tarea = (t2 - t0) * (t3 - t1);
            }
            for (int j = jt; j < jmaxc; ++j) {
                int m = (j << 6) + lane;
                if (m <= t || m >= nc) continue;
                if ((supp >> j) & 1ull) continue;
                float c0, c1, c2, c3;
                if (j < 4) {
                    float4 sr = (j == 0) ? bx0 : (j == 1) ? bx1 : (j == 2) ? bx2 : bx3;
                    c0 = sr.x; c1 = sr.y; c2 = sr.z; c3 = sr.w;
                } else {
                    float4 g = boxes4[bN + order_g[bN + mem[m]]];
                    c0 = g.x; c1 = g.y; c2 = g.z; c3 = g.w;
                }
                if (iou_gt(c0, c1, c2, c3, t0, t1, t2, t3, tarea))
                    supp |= (1ull << j);
            }
        }
    }
}

// ======================= K3: per-batch pack + output ========================
__global__ __launch_bounds__(256)
void k3_pack(const float* __restrict__ scores,
             const float* __restrict__ boxes,
             const unsigned short* __restrict__ order_g,
             const unsigned char*  __restrict__ clsb_g,
             const uint64_t*       __restrict__ kwords_g,
             float* __restrict__ out)
{
    const int b    = blockIdx.x;
    const int tid  = threadIdx.x;
    const int lane = tid & 63;
    const int bN   = b * NN;

    __shared__ uint64_t kw[64];
    __shared__ int      woff[64];
    __shared__ int      total_sh;

    for (int s = tid; s < MAXDET; s += 256) {
        out[OFF_IDX + b * MAXDET + s] = -1.0f;
        out[OFF_SCR + b * MAXDET + s] = 0.0f;
        int ob = OFF_BOX + (b * MAXDET + s) * 4;
        out[ob + 0] = 0.0f; out[ob + 1] = 0.0f;
        out[ob + 2] = 0.0f; out[ob + 3] = 0.0f;
        out[OFF_CLS + b * MAXDET + s] = 0.0f;
    }

    if (tid < 64) {
        uint64_t wd = kwords_g[b * 64 + tid];
        kw[tid] = wd;
        int cnt = __popcll(wd);
        int inc = cnt;
        for (int off = 1; off < 64; off <<= 1) {
            int t = __shfl_up(inc, off, 64);
            if (lane >= off) inc += t;
        }
        woff[tid] = inc - cnt;
        if (tid == 63) total_sh = inc;
    }
    __syncthreads();

    const float4* boxes4 = reinterpret_cast<const float4*>(boxes);
    int ndet = total_sh < MAXDET ? total_sh : MAXDET;
    for (int p = tid; p < NN; p += 256) {
        uint64_t wd = kw[p >> 6];
        if (!((wd >> (p & 63)) & 1ull)) continue;
        int rank = woff[p >> 6] + __popcll(wd & ((1ull << (p & 63)) - 1ull));
        if (rank >= MAXDET) continue;
        int orig = order_g[bN + p];
        out[OFF_SCR + b * MAXDET + rank] = scores[bN + orig];
        float4 g = boxes4[bN + orig];
        int ob = OFF_BOX + (b * MAXDET + rank) * 4;
        out[ob + 0] = g.x; out[ob + 1] = g.y;
        out[ob + 2] = g.z; out[ob + 3] = g.w;
        out[OFF_CLS + b * MAXDET + rank] = (float)clsb_g[bN + p];
    }
    if (tid == 0) out[OFF_NDT + b] = (float)ndet;
}

extern "C" void kernel_launch(void* const* d_in, const int* in_sizes, int n_in,
                              void* d_out, int out_size, void* d_ws, size_t ws_size,
                              hipStream_t stream)
{
    const float* scores  = (const float*)d_in[0];
    const float* boxes   = (const float*)d_in[1];
    const int*   classes = (const int*)d_in[2];
    float*       out     = (float*)d_out;

    char* ws = (char*)d_ws;
    unsigned short* order_g   = (unsigned short*)(ws + WS_ORDER);
    unsigned char*  clsb_g    = (unsigned char*)(ws + WS_CLSB);
    unsigned short* grouped_g = (unsigned short*)(ws + WS_GROUP);
    int*            cbase_g   = (int*)(ws + WS_CBASE);
    uint64_t*       kwords_g  = (uint64_t*)(ws + WS_KW);

    hipLaunchKernelGGL(k1_sort, dim3(NB), dim3(512), 0, stream,
                       scores, classes, order_g, clsb_g, grouped_g, cbase_g, kwords_g);
    hipLaunchKernelGGL(k2_nms, dim3(NB * NCLS), dim3(64), 0, stream,
                       boxes, order_g, grouped_g, cbase_g, kwords_g);
    hipLaunchKernelGGL(k3_pack, dim3(NB), dim3(256), 0, stream,
                       scores, boxes, order_g, clsb_g, kwords_g, out);
}